// Round 3
// baseline (409.868 us; speedup 1.0000x reference)
//
#include <hip/hip_runtime.h>
#include <hip/hip_bf16.h>

#define N_NODES 50000
#define N_EDGES 800000
#define NPAD    50048   // 391*128
#define SCAN_B  196     // ceil(50000/256)

typedef __attribute__((ext_vector_type(8))) short bf16x8;
typedef __attribute__((ext_vector_type(8))) unsigned short u16x8;
typedef __attribute__((ext_vector_type(4))) float f32x4;

__device__ __forceinline__ unsigned short f2bf(float f) {
  union { float f; unsigned u; } x; x.f = f;
  unsigned r = x.u + 0x7fffu + ((x.u >> 16) & 1u);
  return (unsigned short)(r >> 16);
}
__device__ __forceinline__ float bf2f(unsigned short u) {
  union { unsigned u; float f; } x; x.u = ((unsigned)u) << 16;
  return x.f;
}

// async global->LDS, 16B per lane (dest must be linear: base + lane*16)
__device__ __forceinline__ void gload16(const unsigned short* g, unsigned short* l) {
  __builtin_amdgcn_global_load_lds(
      (const __attribute__((address_space(1))) unsigned int*)g,
      (__attribute__((address_space(3))) unsigned int*)l, 16, 0, 0);
}

// ---------------- CSR build ----------------
__global__ void hist_kernel(const int* __restrict__ dst, int* __restrict__ counts, int E) {
  int e = blockIdx.x * 256 + threadIdx.x;
  if (e < E) atomicAdd(&counts[dst[e]], 1);
}

__global__ __launch_bounds__(256) void scan1_kernel(const int* __restrict__ counts,
                                                    int* __restrict__ tmp, int* __restrict__ bsum, int n) {
  __shared__ int sm[256];
  int i = blockIdx.x * 256 + threadIdx.x;
  int v = (i < n) ? counts[i] : 0;
  sm[threadIdx.x] = v;
  __syncthreads();
  for (int off = 1; off < 256; off <<= 1) {
    int t = (threadIdx.x >= off) ? sm[threadIdx.x - off] : 0;
    __syncthreads();
    sm[threadIdx.x] += t;
    __syncthreads();
  }
  if (i < n) tmp[i] = sm[threadIdx.x] - v;
  if (threadIdx.x == 255) bsum[blockIdx.x] = sm[255];
}

__global__ __launch_bounds__(256) void scan2_kernel(const int* __restrict__ bsum,
                                                    int* __restrict__ bbase, int nb) {
  __shared__ int sm[256];
  int v = (threadIdx.x < nb) ? bsum[threadIdx.x] : 0;
  sm[threadIdx.x] = v;
  __syncthreads();
  for (int off = 1; off < 256; off <<= 1) {
    int t = (threadIdx.x >= off) ? sm[threadIdx.x - off] : 0;
    __syncthreads();
    sm[threadIdx.x] += t;
    __syncthreads();
  }
  if (threadIdx.x < nb) bbase[threadIdx.x] = sm[threadIdx.x] - v;
}

__global__ __launch_bounds__(256) void scan3_kernel(const int* __restrict__ tmp,
                                                    const int* __restrict__ bbase,
                                                    int* __restrict__ offsets, int* __restrict__ cursor,
                                                    int n, int E) {
  int i = blockIdx.x * 256 + threadIdx.x;
  if (i < n) {
    int o = tmp[i] + bbase[blockIdx.x];
    offsets[i] = o;
    cursor[i] = o;
  }
  if (i == 0) offsets[n] = E;
}

__global__ void scatter_kernel(const int* __restrict__ src, const int* __restrict__ dst,
                               int* __restrict__ cursor, int* __restrict__ csr_src, int E) {
  int e = blockIdx.x * 256 + threadIdx.x;
  if (e < E) {
    int pos = atomicAdd(&cursor[dst[e]], 1);
    csr_src[pos] = src[e];
  }
}

// ---------------- packing / conversion ----------------
__global__ void convert_x_kernel(const float* __restrict__ x, unsigned short* __restrict__ xb,
                                 int total_real, int total_pad) {
  long i = ((long)blockIdx.x * 256 + threadIdx.x) * 8;
  if (i >= total_pad) return;
  u16x8 o;
  if (i < total_real) {
    float4 v0 = *(const float4*)&x[i];
    float4 v1 = *(const float4*)&x[i + 4];
    o[0] = (short)f2bf(v0.x); o[1] = (short)f2bf(v0.y);
    o[2] = (short)f2bf(v0.z); o[3] = (short)f2bf(v0.w);
    o[4] = (short)f2bf(v1.x); o[5] = (short)f2bf(v1.y);
    o[6] = (short)f2bf(v1.z); o[7] = (short)f2bf(v1.w);
  } else {
    o = (u16x8)0;
  }
  *(u16x8*)&xb[i] = o;
}

__global__ void pack_w1_kernel(const float* __restrict__ Wq, const float* __restrict__ Wk,
                               const float* __restrict__ Wv, const float* __restrict__ Ws,
                               const float* __restrict__ bq, const float* __restrict__ bk,
                               const float* __restrict__ bv, const float* __restrict__ bs_,
                               unsigned short* __restrict__ wbt, float* __restrict__ bias1) {
  int idx = blockIdx.x * 256 + threadIdx.x;
  if (idx >= 1024 * 384) return;
  int n = idx / 384, k = idx - n * 384;
  int blk = n >> 8, cc = n & 255;
  const float* W = (blk == 0) ? Wq : (blk == 1) ? Wk : (blk == 2) ? Wv : Ws;
  wbt[idx] = f2bf(W[(long)k * 256 + cc]);   // wbt[n][k] = W[k][cc]  (transposed)
  if (k == 0) {
    const float* b = (blk == 0) ? bq : (blk == 1) ? bk : (blk == 2) ? bv : bs_;
    bias1[n] = b[cc];
  }
}

__global__ void pack_w2_kernel(const float* __restrict__ Wq, const float* __restrict__ Wk,
                               const float* __restrict__ Wv, const float* __restrict__ Ws,
                               const float* __restrict__ bq, const float* __restrict__ bk,
                               const float* __restrict__ bv, const float* __restrict__ bs_,
                               float* __restrict__ w2t, float* __restrict__ bias2) {
  int idx = blockIdx.x * 256 + threadIdx.x;
  if (idx >= 20 * 256) return;
  int c = idx / 256, k = idx - c * 256;
  int blk = c / 5, cc = c - blk * 5;
  const float* W = (blk == 0) ? Wq : (blk == 1) ? Wk : (blk == 2) ? Wv : Ws;
  w2t[idx] = W[(long)k * 5 + cc];           // w2t[c][k] = W[k][cc]
  if (k == 0) {
    const float* b = (blk == 0) ? bq : (blk == 1) ? bk : (blk == 2) ? bv : bs_;
    bias2[c] = b[cc];
  }
}

// ---------------- layer-1 fused QKVS GEMM (bf16 MFMA) ----------------
// Y[NPAD][1024] = xb[NPAD][384] @ W[384][1024] + bias
// BM=128, BN=256, BK=32, 512 threads; global_load_lds staging with
// XOR-swizzled source (slot ^= (r ^ r>>2)&3) so ds_read_b128 is 2-way max.
__global__ __launch_bounds__(512) void gemm1_kernel(
    const unsigned short* __restrict__ xb, const unsigned short* __restrict__ wbt,
    const float* __restrict__ bias,
    unsigned short* __restrict__ qb, unsigned short* __restrict__ kb,
    unsigned short* __restrict__ vb, unsigned short* __restrict__ s1b) {
  __shared__ unsigned short As[128 * 32];   // 8 KB
  __shared__ unsigned short Bs[256 * 32];   // 16 KB
  int tid = threadIdx.x;
  long m0 = (long)blockIdx.x * 128;
  int n0 = blockIdx.y * 256;
  int w = tid >> 6, l = tid & 63;
  int wr = (w >> 2) * 64, wc = (w & 3) * 64;
  int lr = l & 15, c0 = l >> 4;
  int sw = (lr ^ (lr >> 2)) & 3;
  int swoff = (c0 ^ sw) * 8;                // fragment-read chunk (swizzled), loop-invariant
  f32x4 acc[4][4] = {};
  // staging addresses: lane tid stages LDS bytes [tid*16, tid*16+16)
  int rs = tid >> 2, ss = tid & 3;
  int fa = (rs ^ (rs >> 2)) & 3;
  int fb1 = ((rs + 128) ^ ((rs + 128) >> 2)) & 3;
  const unsigned short* gA  = xb + (m0 + rs) * 384 + ((ss ^ fa) * 8);
  const unsigned short* gB0 = wbt + (long)(n0 + rs) * 384 + ((ss ^ fa) * 8);
  const unsigned short* gB1 = wbt + (long)(n0 + rs + 128) * 384 + ((ss ^ fb1) * 8);
  for (int kt = 0; kt < 12; ++kt) {
    int ko = kt * 32;
    __syncthreads();   // previous tile consumed
    gload16(gA + ko, &As[tid * 8]);
    gload16(gB0 + ko, &Bs[tid * 8]);
    gload16(gB1 + ko, &Bs[4096 + tid * 8]);
    __syncthreads();   // drains vmcnt: tile ready
    bf16x8 af[4], bfv[4];
#pragma unroll
    for (int mf = 0; mf < 4; ++mf) af[mf] = *(const bf16x8*)&As[(wr + mf * 16 + lr) * 32 + swoff];
#pragma unroll
    for (int nf = 0; nf < 4; ++nf) bfv[nf] = *(const bf16x8*)&Bs[(wc + nf * 16 + lr) * 32 + swoff];
#pragma unroll
    for (int mf = 0; mf < 4; ++mf)
#pragma unroll
      for (int nf = 0; nf < 4; ++nf)
        acc[mf][nf] = __builtin_amdgcn_mfma_f32_16x16x32_bf16(af[mf], bfv[nf], acc[mf][nf], 0, 0, 0);
  }
  unsigned short* op = (blockIdx.y == 0) ? qb : (blockIdx.y == 1) ? kb : (blockIdx.y == 2) ? vb : s1b;
#pragma unroll
  for (int nf = 0; nf < 4; ++nf) {
    int col = n0 + wc + nf * 16 + lr;
    int cc = col & 255;
    float bv = bias[col];
#pragma unroll
    for (int mf = 0; mf < 4; ++mf) {
      long row = m0 + wr + mf * 16 + (l >> 4) * 4;
#pragma unroll
      for (int i = 0; i < 4; ++i) {
        op[(row + i) * 256 + cc] = f2bf(acc[mf][nf][i] + bv);
      }
    }
  }
}

// ---------------- layer-1 fused attention aggregation ----------------
// one wave per node; 16-lane group g handles edge i+g (4 edges/round,
// 2 rounds in flight = 8 edges); lane owns 16 channels (= quarter of one head
// per 4-lane cluster -> logit reduce is shfl_xor 1,2).
__global__ __launch_bounds__(256) void agg1_kernel(
    const unsigned short* __restrict__ qb, const unsigned short* __restrict__ kb,
    const unsigned short* __restrict__ vb, unsigned short* s1b,
    const int* __restrict__ offsets, const int* __restrict__ csr_src) {
  int w = threadIdx.x >> 6, l = threadIdx.x & 63;
  int n = blockIdx.x * 4 + w;
  if (n >= N_NODES) return;
  int g = l >> 4;            // edge slot 0..3
  int sub = l & 15;          // channel block 0..15 (head = sub>>2)
  long chb = (long)sub * 16;
  float qf[16];
  {
    const unsigned short* qrow = qb + (long)n * 256 + chb;
    u16x8 q0 = *(const u16x8*)qrow;
    u16x8 q1 = *(const u16x8*)(qrow + 8);
#pragma unroll
    for (int j = 0; j < 8; ++j) {
      qf[j] = bf2f((unsigned short)q0[j]) * 0.125f;
      qf[8 + j] = bf2f((unsigned short)q1[j]) * 0.125f;
    }
  }
  float acc[16] = {};
  float se = 0.f;
  int i0 = offsets[n], i1 = offsets[n + 1];
  for (int i = i0; i < i1; i += 8) {
    int ia = i + g, ib = i + 4 + g;
    int sa = csr_src[ia < i1 ? ia : i1 - 1];
    int sb = csr_src[ib < i1 ? ib : i1 - 1];
    const unsigned short* pka = kb + (long)sa * 256 + chb;
    const unsigned short* pkb = kb + (long)sb * 256 + chb;
    const unsigned short* pva = vb + (long)sa * 256 + chb;
    const unsigned short* pvb = vb + (long)sb * 256 + chb;
    u16x8 ka0 = *(const u16x8*)pka;      u16x8 ka1 = *(const u16x8*)(pka + 8);
    u16x8 kb0 = *(const u16x8*)pkb;      u16x8 kb1 = *(const u16x8*)(pkb + 8);
    u16x8 va0 = *(const u16x8*)pva;      u16x8 va1 = *(const u16x8*)(pva + 8);
    u16x8 vb0 = *(const u16x8*)pvb;      u16x8 vb1 = *(const u16x8*)(pvb + 8);
    float pa = 0.f, pb = 0.f;
#pragma unroll
    for (int j = 0; j < 8; ++j) {
      pa += qf[j] * bf2f((unsigned short)ka0[j]) + qf[8 + j] * bf2f((unsigned short)ka1[j]);
      pb += qf[j] * bf2f((unsigned short)kb0[j]) + qf[8 + j] * bf2f((unsigned short)kb1[j]);
    }
    pa += __shfl_xor(pa, 1); pa += __shfl_xor(pa, 2);
    pb += __shfl_xor(pb, 1); pb += __shfl_xor(pb, 2);
    float ea = (ia < i1) ? __expf(pa) : 0.f;
    float eb = (ib < i1) ? __expf(pb) : 0.f;
    se += ea + eb;
#pragma unroll
    for (int j = 0; j < 8; ++j) {
      acc[j]     += ea * bf2f((unsigned short)va0[j]) + eb * bf2f((unsigned short)vb0[j]);
      acc[8 + j] += ea * bf2f((unsigned short)va1[j]) + eb * bf2f((unsigned short)vb1[j]);
    }
  }
  // combine the 4 edge-groups (xor 16/32 preserves sub -> per-head se correct)
#pragma unroll
  for (int j = 0; j < 16; ++j) {
    acc[j] += __shfl_xor(acc[j], 16);
    acc[j] += __shfl_xor(acc[j], 32);
  }
  se += __shfl_xor(se, 16);
  se += __shfl_xor(se, 32);
  if (g == 0) {
    float inv = 1.0f / (se + 1e-16f);
    long ob = (long)n * 256 + chb;
    u16x8 sv0 = *(const u16x8*)&s1b[ob];
    u16x8 sv1 = *(const u16x8*)&s1b[ob + 8];
    u16x8 h0, h1;
#pragma unroll
    for (int j = 0; j < 8; ++j) {
      h0[j] = (short)f2bf(fmaxf(acc[j] * inv + bf2f((unsigned short)sv0[j]), 0.f));
      h1[j] = (short)f2bf(fmaxf(acc[8 + j] * inv + bf2f((unsigned short)sv1[j]), 0.f));
    }
    *(u16x8*)&s1b[ob] = h0;
    *(u16x8*)&s1b[ob + 8] = h1;
  }
}

// ---------------- layer-2 linear (h[256] -> 20 outs per row) ----------------
__global__ __launch_bounds__(256) void lin2_kernel(const unsigned short* __restrict__ hb,
                                                   const float* __restrict__ w2t,
                                                   const float* __restrict__ bias2,
                                                   float* __restrict__ qkvs2) {
  __shared__ float ws[20 * 256];
  __shared__ float bs[20];
  for (int i = threadIdx.x; i < 20 * 256; i += 256) ws[i] = w2t[i];
  if (threadIdx.x < 20) bs[threadIdx.x] = bias2[threadIdx.x];
  __syncthreads();
  int w = threadIdx.x >> 6, l = threadIdx.x & 63;
  int n = blockIdx.x * 4 + w;
  if (n >= N_NODES) return;
  ushort4 hu = *(const ushort4*)&hb[(long)n * 256 + l * 4];
  float h0 = bf2f(hu.x), h1 = bf2f(hu.y), h2 = bf2f(hu.z), h3 = bf2f(hu.w);
  float myout = 0.f;
#pragma unroll
  for (int c = 0; c < 20; ++c) {
    float4 wv = *(const float4*)&ws[c * 256 + l * 4];
    float pp = h0 * wv.x + h1 * wv.y + h2 * wv.z + h3 * wv.w;
    pp += __shfl_xor(pp, 1);  pp += __shfl_xor(pp, 2);  pp += __shfl_xor(pp, 4);
    pp += __shfl_xor(pp, 8);  pp += __shfl_xor(pp, 16); pp += __shfl_xor(pp, 32);
    if (l == c) myout = pp + bs[c];
  }
  if (l < 20) qkvs2[(long)n * 20 + l] = myout;
}

// ---------------- layer-2 fused attention (1 thread per node) ----------------
__global__ void agg2_kernel(const float* __restrict__ qkvs2,
                            const int* __restrict__ offsets, const int* __restrict__ csr_src,
                            float* __restrict__ out) {
  int n = blockIdx.x * 256 + threadIdx.x;
  if (n >= N_NODES) return;
  const float* bn = &qkvs2[(long)n * 20];
  const float is5 = 0.4472135954999579f;  // 1/sqrt(5)
  float q[5], acc[5] = {0, 0, 0, 0, 0}, se = 0.f;
#pragma unroll
  for (int c = 0; c < 5; ++c) q[c] = bn[c] * is5;
  int i0 = offsets[n], i1 = offsets[n + 1];
  for (int i = i0; i < i1; ++i) {
    int s = csr_src[i];
    const float* bsrc = &qkvs2[(long)s * 20];
    float lg = q[0] * bsrc[5] + q[1] * bsrc[6] + q[2] * bsrc[7] + q[3] * bsrc[8] + q[4] * bsrc[9];
    float ee = __expf(lg);
    se += ee;
    acc[0] += ee * bsrc[10]; acc[1] += ee * bsrc[11]; acc[2] += ee * bsrc[12];
    acc[3] += ee * bsrc[13]; acc[4] += ee * bsrc[14];
  }
  float inv = 1.f / (se + 1e-16f);
#pragma unroll
  for (int c = 0; c < 5; ++c) out[(long)n * 5 + c] = acc[c] * inv + bn[15 + c];
}

// ---------------- launch ----------------
extern "C" void kernel_launch(void* const* d_in, const int* in_sizes, int n_in,
                              void* d_out, int out_size, void* d_ws, size_t ws_size,
                              hipStream_t stream) {
  (void)in_sizes; (void)n_in; (void)out_size; (void)ws_size;
  const float* x   = (const float*)d_in[0];
  const int* eidx  = (const int*)d_in[1];
  const int* esrc  = eidx;
  const int* edst  = eidx + N_EDGES;
  const float* Wq1 = (const float*)d_in[2];  const float* bq1 = (const float*)d_in[3];
  const float* Wk1 = (const float*)d_in[4];  const float* bk1 = (const float*)d_in[5];
  const float* Wv1 = (const float*)d_in[6];  const float* bv1 = (const float*)d_in[7];
  const float* Ws1 = (const float*)d_in[8];  const float* bs1 = (const float*)d_in[9];
  const float* Wq2 = (const float*)d_in[10]; const float* bq2 = (const float*)d_in[11];
  const float* Wk2 = (const float*)d_in[12]; const float* bk2 = (const float*)d_in[13];
  const float* Wv2 = (const float*)d_in[14]; const float* bv2 = (const float*)d_in[15];
  const float* Ws2 = (const float*)d_in[16]; const float* bs2 = (const float*)d_in[17];

  char* p = (char*)d_ws;
  auto take = [&](size_t bytes) { char* r = p; p += (bytes + 255) & ~(size_t)255; return r; };
  unsigned short* xb  = (unsigned short*)take((size_t)NPAD * 384 * 2);
  unsigned short* wbt = (unsigned short*)take((size_t)1024 * 384 * 2);
  float* bias1        = (float*)take(1024 * 4);
  unsigned short* qb  = (unsigned short*)take((size_t)NPAD * 256 * 2);
  unsigned short* kb  = (unsigned short*)take((size_t)NPAD * 256 * 2);
  unsigned short* vb  = (unsigned short*)take((size_t)NPAD * 256 * 2);
  unsigned short* s1b = (unsigned short*)take((size_t)NPAD * 256 * 2);
  float* w2t          = (float*)take(20 * 256 * 4);
  float* bias2        = (float*)take(32 * 4);
  float* qkvs2        = (float*)take((size_t)NPAD * 20 * 4);
  int* counts         = (int*)take((size_t)N_NODES * 4);
  int* offsets        = (int*)take((size_t)(N_NODES + 1) * 4);
  int* cursor         = (int*)take((size_t)N_NODES * 4);
  int* csr_src        = (int*)take((size_t)N_EDGES * 4);
  int* scan_tmp       = (int*)take((size_t)N_NODES * 4);
  int* scan_bsum      = (int*)take(256 * 4);
  int* scan_bbase     = (int*)take(256 * 4);

  hipMemsetAsync(counts, 0, (size_t)N_NODES * 4, stream);
  hist_kernel<<<(N_EDGES + 255) / 256, 256, 0, stream>>>(edst, counts, N_EDGES);
  scan1_kernel<<<SCAN_B, 256, 0, stream>>>(counts, scan_tmp, scan_bsum, N_NODES);
  scan2_kernel<<<1, 256, 0, stream>>>(scan_bsum, scan_bbase, SCAN_B);
  scan3_kernel<<<SCAN_B, 256, 0, stream>>>(scan_tmp, scan_bbase, offsets, cursor, N_NODES, N_EDGES);
  scatter_kernel<<<(N_EDGES + 255) / 256, 256, 0, stream>>>(esrc, edst, cursor, csr_src, N_EDGES);
  convert_x_kernel<<<(NPAD * 384 / 8 + 255) / 256, 256, 0, stream>>>(x, xb, N_NODES * 384, NPAD * 384);
  pack_w1_kernel<<<(1024 * 384 + 255) / 256, 256, 0, stream>>>(Wq1, Wk1, Wv1, Ws1, bq1, bk1, bv1, bs1, wbt, bias1);
  pack_w2_kernel<<<(20 * 256 + 255) / 256, 256, 0, stream>>>(Wq2, Wk2, Wv2, Ws2, bq2, bk2, bv2, bs2, w2t, bias2);
  gemm1_kernel<<<dim3(NPAD / 128, 4), 512, 0, stream>>>(xb, wbt, bias1, qb, kb, vb, s1b);
  agg1_kernel<<<(N_NODES + 3) / 4, 256, 0, stream>>>(qb, kb, vb, s1b, offsets, csr_src);
  lin2_kernel<<<(N_NODES + 3) / 4, 256, 0, stream>>>(s1b, w2t, bias2, qkvs2);
  agg2_kernel<<<(N_NODES + 255) / 256, 256, 0, stream>>>(qkvs2, offsets, csr_src, (float*)d_out);
}

// Round 4
// 370.125 us; speedup vs baseline: 1.1074x; 1.1074x over previous
//
#include <hip/hip_runtime.h>
#include <hip/hip_bf16.h>

#define N_NODES 50000
#define N_EDGES 800000
#define NPAD    50048   // 391*128
#define SCAN_B  196     // ceil(50000/256)

typedef __attribute__((ext_vector_type(8))) short bf16x8;
typedef __attribute__((ext_vector_type(8))) unsigned short u16x8;
typedef __attribute__((ext_vector_type(4))) float f32x4;

__device__ __forceinline__ unsigned short f2bf(float f) {
  union { float f; unsigned u; } x; x.f = f;
  unsigned r = x.u + 0x7fffu + ((x.u >> 16) & 1u);
  return (unsigned short)(r >> 16);
}
__device__ __forceinline__ float bf2f(unsigned short u) {
  union { unsigned u; float f; } x; x.u = ((unsigned)u) << 16;
  return x.f;
}
// biased i8, scale 16: b = clamp(round(v*16)+128, 0, 255); v = (b-128)/16
__device__ __forceinline__ unsigned char enc8(float v) {
  float t = fminf(fmaxf(fmaf(v, 16.f, 128.5f), 0.f), 255.f);
  return (unsigned char)(int)t;
}

// async global->LDS, 16B per lane (dest must be linear: base + lane*16)
__device__ __forceinline__ void gload16(const unsigned short* g, unsigned short* l) {
  __builtin_amdgcn_global_load_lds(
      (const __attribute__((address_space(1))) unsigned int*)g,
      (__attribute__((address_space(3))) unsigned int*)l, 16, 0, 0);
}

// ---------------- CSR build ----------------
__global__ void hist_kernel(const int* __restrict__ dst, int* __restrict__ counts, int E) {
  int e = blockIdx.x * 256 + threadIdx.x;
  if (e < E) atomicAdd(&counts[dst[e]], 1);
}

__global__ __launch_bounds__(256) void scan1_kernel(const int* __restrict__ counts,
                                                    int* __restrict__ tmp, int* __restrict__ bsum, int n) {
  __shared__ int sm[256];
  int i = blockIdx.x * 256 + threadIdx.x;
  int v = (i < n) ? counts[i] : 0;
  sm[threadIdx.x] = v;
  __syncthreads();
  for (int off = 1; off < 256; off <<= 1) {
    int t = (threadIdx.x >= off) ? sm[threadIdx.x - off] : 0;
    __syncthreads();
    sm[threadIdx.x] += t;
    __syncthreads();
  }
  if (i < n) tmp[i] = sm[threadIdx.x] - v;
  if (threadIdx.x == 255) bsum[blockIdx.x] = sm[255];
}

__global__ __launch_bounds__(256) void scan2_kernel(const int* __restrict__ bsum,
                                                    int* __restrict__ bbase, int nb) {
  __shared__ int sm[256];
  int v = (threadIdx.x < nb) ? bsum[threadIdx.x] : 0;
  sm[threadIdx.x] = v;
  __syncthreads();
  for (int off = 1; off < 256; off <<= 1) {
    int t = (threadIdx.x >= off) ? sm[threadIdx.x - off] : 0;
    __syncthreads();
    sm[threadIdx.x] += t;
    __syncthreads();
  }
  if (threadIdx.x < nb) bbase[threadIdx.x] = sm[threadIdx.x] - v;
}

__global__ __launch_bounds__(256) void scan3_kernel(const int* __restrict__ tmp,
                                                    const int* __restrict__ bbase,
                                                    int* __restrict__ offsets, int* __restrict__ cursor,
                                                    int n, int E) {
  int i = blockIdx.x * 256 + threadIdx.x;
  if (i < n) {
    int o = tmp[i] + bbase[blockIdx.x];
    offsets[i] = o;
    cursor[i] = o;
  }
  if (i == 0) offsets[n] = E;
}

__global__ void scatter_kernel(const int* __restrict__ src, const int* __restrict__ dst,
                               int* __restrict__ cursor, int* __restrict__ csr_src, int E) {
  int e = blockIdx.x * 256 + threadIdx.x;
  if (e < E) {
    int pos = atomicAdd(&cursor[dst[e]], 1);
    csr_src[pos] = src[e];
  }
}

// ---------------- packing / conversion ----------------
__global__ void convert_x_kernel(const float* __restrict__ x, unsigned short* __restrict__ xb,
                                 int total_real, int total_pad) {
  long i = ((long)blockIdx.x * 256 + threadIdx.x) * 8;
  if (i >= total_pad) return;
  u16x8 o;
  if (i < total_real) {
    float4 v0 = *(const float4*)&x[i];
    float4 v1 = *(const float4*)&x[i + 4];
    o[0] = (short)f2bf(v0.x); o[1] = (short)f2bf(v0.y);
    o[2] = (short)f2bf(v0.z); o[3] = (short)f2bf(v0.w);
    o[4] = (short)f2bf(v1.x); o[5] = (short)f2bf(v1.y);
    o[6] = (short)f2bf(v1.z); o[7] = (short)f2bf(v1.w);
  } else {
    o = (u16x8)0;
  }
  *(u16x8*)&xb[i] = o;
}

__global__ void pack_w1_kernel(const float* __restrict__ Wq, const float* __restrict__ Wk,
                               const float* __restrict__ Wv, const float* __restrict__ Ws,
                               const float* __restrict__ bq, const float* __restrict__ bk,
                               const float* __restrict__ bv, const float* __restrict__ bs_,
                               unsigned short* __restrict__ wbt, float* __restrict__ bias1) {
  int idx = blockIdx.x * 256 + threadIdx.x;
  if (idx >= 1024 * 384) return;
  int n = idx / 384, k = idx - n * 384;
  int blk = n >> 8, cc = n & 255;
  const float* W = (blk == 0) ? Wq : (blk == 1) ? Wk : (blk == 2) ? Wv : Ws;
  wbt[idx] = f2bf(W[(long)k * 256 + cc]);   // wbt[n][k] = W[k][cc]  (transposed)
  if (k == 0) {
    const float* b = (blk == 0) ? bq : (blk == 1) ? bk : (blk == 2) ? bv : bs_;
    bias1[n] = b[cc];
  }
}

__global__ void pack_w2_kernel(const float* __restrict__ Wq, const float* __restrict__ Wk,
                               const float* __restrict__ Wv, const float* __restrict__ Ws,
                               const float* __restrict__ bq, const float* __restrict__ bk,
                               const float* __restrict__ bv, const float* __restrict__ bs_,
                               float* __restrict__ w2t, float* __restrict__ bias2) {
  int idx = blockIdx.x * 256 + threadIdx.x;
  if (idx >= 20 * 256) return;
  int c = idx / 256, k = idx - c * 256;
  int blk = c / 5, cc = c - blk * 5;
  const float* W = (blk == 0) ? Wq : (blk == 1) ? Wk : (blk == 2) ? Wv : Ws;
  w2t[idx] = W[(long)k * 5 + cc];           // w2t[c][k] = W[k][cc]
  if (k == 0) {
    const float* b = (blk == 0) ? bq : (blk == 1) ? bk : (blk == 2) ? bv : bs_;
    bias2[c] = b[cc];
  }
}

// ---------------- layer-1 fused QKVS GEMM (bf16 MFMA, 2-phase dbuf) ----------------
// Y[NPAD][1024] = xb[NPAD][384] @ W[384][1024] + bias
// outputs: y=0 -> q (bf16 [N][256]); y=1 -> k (i8 -> kvb[row*512+cc]);
//          y=2 -> v (i8 -> kvb[row*512+256+cc]); y=3 -> skip (bf16 [N][256])
__global__ __launch_bounds__(512) void gemm1_kernel(
    const unsigned short* __restrict__ xb, const unsigned short* __restrict__ wbt,
    const float* __restrict__ bias,
    unsigned short* __restrict__ qb, unsigned char* __restrict__ kvb,
    unsigned short* __restrict__ s1b) {
  __shared__ unsigned short As[2][128 * 32];   // 2 x 8 KB
  __shared__ unsigned short Bs[2][256 * 32];   // 2 x 16 KB
  int tid = threadIdx.x;
  long m0 = (long)blockIdx.x * 128;
  int n0 = blockIdx.y * 256;
  int w = tid >> 6, l = tid & 63;
  int wr = (w >> 2) * 64, wc = (w & 3) * 64;
  int lr = l & 15, c0 = l >> 4;
  int sw = (lr ^ (lr >> 2)) & 3;
  int swoff = (c0 ^ sw) * 8;                // swizzled fragment chunk, loop-invariant
  f32x4 acc[4][4] = {};
  int rs = tid >> 2, ss = tid & 3;
  int fa = (rs ^ (rs >> 2)) & 3;
  int fb1 = ((rs + 128) ^ ((rs + 128) >> 2)) & 3;
  const unsigned short* gA  = xb + (m0 + rs) * 384 + ((ss ^ fa) * 8);
  const unsigned short* gB0 = wbt + (long)(n0 + rs) * 384 + ((ss ^ fa) * 8);
  const unsigned short* gB1 = wbt + (long)(n0 + rs + 128) * 384 + ((ss ^ fb1) * 8);
  // prologue: stage tile 0 into buf 0
  gload16(gA, &As[0][tid * 8]);
  gload16(gB0, &Bs[0][tid * 8]);
  gload16(gB1, &Bs[0][4096 + tid * 8]);
  __syncthreads();                           // drains vmcnt: tile 0 ready
  for (int kt = 0; kt < 12; ++kt) {
    int b = kt & 1;
    if (kt < 11) {                           // stage next tile while computing
      int ko = (kt + 1) * 32;
      gload16(gA + ko, &As[b ^ 1][tid * 8]);
      gload16(gB0 + ko, &Bs[b ^ 1][tid * 8]);
      gload16(gB1 + ko, &Bs[b ^ 1][4096 + tid * 8]);
    }
    bf16x8 af[4], bfv[4];
#pragma unroll
    for (int mf = 0; mf < 4; ++mf) af[mf] = *(const bf16x8*)&As[b][(wr + mf * 16 + lr) * 32 + swoff];
#pragma unroll
    for (int nf = 0; nf < 4; ++nf) bfv[nf] = *(const bf16x8*)&Bs[b][(wc + nf * 16 + lr) * 32 + swoff];
#pragma unroll
    for (int mf = 0; mf < 4; ++mf)
#pragma unroll
      for (int nf = 0; nf < 4; ++nf)
        acc[mf][nf] = __builtin_amdgcn_mfma_f32_16x16x32_bf16(af[mf], bfv[nf], acc[mf][nf], 0, 0, 0);
    __syncthreads();                         // drains vmcnt: next tile ready, buf b free
  }
  int y = blockIdx.y;
#pragma unroll
  for (int nf = 0; nf < 4; ++nf) {
    int col = n0 + wc + nf * 16 + lr;
    int cc = col & 255;
    float bv = bias[col];
#pragma unroll
    for (int mf = 0; mf < 4; ++mf) {
      long row = m0 + wr + mf * 16 + (l >> 4) * 4;
#pragma unroll
      for (int i = 0; i < 4; ++i) {
        float v = acc[mf][nf][i] + bv;
        long r = row + i;
        if (y == 0) qb[r * 256 + cc] = f2bf(v);
        else if (y == 1) kvb[r * 512 + cc] = enc8(v);
        else if (y == 2) kvb[r * 512 + 256 + cc] = enc8(v);
        else s1b[r * 256 + cc] = f2bf(v);
      }
    }
  }
}

// ---------------- layer-1 fused attention aggregation (i8 kv) ----------------
// one wave per node; 16-lane group g handles edge i+g; lane owns 16 channels.
// kv record: 512 B, k bytes 0-255, v bytes 256-511; b = v*16+128.
// logit = sum q'*b - 128*sum q'  (q' = q/(8*16)); v_attn = (sum(e*b)/sum(e))/16 - 8.
__global__ __launch_bounds__(256) void agg1_kernel(
    const unsigned short* __restrict__ qb, const unsigned char* __restrict__ kvb,
    unsigned short* s1b,
    const int* __restrict__ offsets, const int* __restrict__ csr_src) {
  int w = threadIdx.x >> 6, l = threadIdx.x & 63;
  int n = blockIdx.x * 4 + w;
  if (n >= N_NODES) return;
  int g = l >> 4;            // edge slot 0..3
  int sub = l & 15;          // channel block (head = sub>>2)
  float qf[16];
  float qs = 0.f;
  {
    const unsigned short* qrow = qb + (long)n * 256 + sub * 16;
    u16x8 q0 = *(const u16x8*)qrow;
    u16x8 q1 = *(const u16x8*)(qrow + 8);
#pragma unroll
    for (int j = 0; j < 8; ++j) {
      qf[j] = bf2f((unsigned short)q0[j]) * 0.0078125f;       // 1/(8*16)
      qf[8 + j] = bf2f((unsigned short)q1[j]) * 0.0078125f;
    }
#pragma unroll
    for (int j = 0; j < 16; ++j) qs += qf[j];
    qs += __shfl_xor(qs, 1); qs += __shfl_xor(qs, 2);         // head-level sum
  }
  float pc = 128.f * qs;
  float acc[16] = {};
  float se = 0.f;
  int i0 = offsets[n], i1 = offsets[n + 1];
#define DOT4(P, W, B) \
  P = fmaf(qf[(B) + 0], (float)((W) & 0xffu), P); \
  P = fmaf(qf[(B) + 1], (float)(((W) >> 8) & 0xffu), P); \
  P = fmaf(qf[(B) + 2], (float)(((W) >> 16) & 0xffu), P); \
  P = fmaf(qf[(B) + 3], (float)((W) >> 24), P);
#define VACC(E, W, B) \
  acc[(B) + 0] = fmaf(E, (float)((W) & 0xffu), acc[(B) + 0]); \
  acc[(B) + 1] = fmaf(E, (float)(((W) >> 8) & 0xffu), acc[(B) + 1]); \
  acc[(B) + 2] = fmaf(E, (float)(((W) >> 16) & 0xffu), acc[(B) + 2]); \
  acc[(B) + 3] = fmaf(E, (float)((W) >> 24), acc[(B) + 3]);
  for (int i = i0; i < i1; i += 8) {
    int ia = i + g, ib = i + 4 + g;
    int sa = csr_src[ia < i1 ? ia : i1 - 1];
    int sb = csr_src[ib < i1 ? ib : i1 - 1];
    const uint4* pa = (const uint4*)(kvb + (long)sa * 512 + sub * 16);
    const uint4* pb = (const uint4*)(kvb + (long)sb * 512 + sub * 16);
    uint4 ka = pa[0], va = pa[16];     // +16 uint4 = +256 B
    uint4 kw = pb[0], vw = pb[16];
    float pa_ = 0.f, pb_ = 0.f;
    DOT4(pa_, ka.x, 0) DOT4(pa_, ka.y, 4) DOT4(pa_, ka.z, 8) DOT4(pa_, ka.w, 12)
    DOT4(pb_, kw.x, 0) DOT4(pb_, kw.y, 4) DOT4(pb_, kw.z, 8) DOT4(pb_, kw.w, 12)
    pa_ += __shfl_xor(pa_, 1); pa_ += __shfl_xor(pa_, 2);
    pb_ += __shfl_xor(pb_, 1); pb_ += __shfl_xor(pb_, 2);
    float ea = (ia < i1) ? __expf(pa_ - pc) : 0.f;
    float eb = (ib < i1) ? __expf(pb_ - pc) : 0.f;
    se += ea + eb;
    VACC(ea, va.x, 0) VACC(ea, va.y, 4) VACC(ea, va.z, 8) VACC(ea, va.w, 12)
    VACC(eb, vw.x, 0) VACC(eb, vw.y, 4) VACC(eb, vw.z, 8) VACC(eb, vw.w, 12)
  }
#undef DOT4
#undef VACC
#pragma unroll
  for (int j = 0; j < 16; ++j) {
    acc[j] += __shfl_xor(acc[j], 16);
    acc[j] += __shfl_xor(acc[j], 32);
  }
  se += __shfl_xor(se, 16);
  se += __shfl_xor(se, 32);
  if (g == 0) {
    float inv = (se > 0.f) ? 1.0f / se : 0.f;
    float bias = (se > 0.f) ? -8.0f : 0.f;   // deg-0 node: attn out = 0
    long ob = (long)n * 256 + sub * 16;
    u16x8 sv0 = *(const u16x8*)&s1b[ob];
    u16x8 sv1 = *(const u16x8*)&s1b[ob + 8];
    u16x8 h0, h1;
#pragma unroll
    for (int j = 0; j < 8; ++j) {
      float v0 = fmaf(acc[j] * inv, 0.0625f, bias);
      float v1 = fmaf(acc[8 + j] * inv, 0.0625f, bias);
      h0[j] = (short)f2bf(fmaxf(v0 + bf2f((unsigned short)sv0[j]), 0.f));
      h1[j] = (short)f2bf(fmaxf(v1 + bf2f((unsigned short)sv1[j]), 0.f));
    }
    *(u16x8*)&s1b[ob] = h0;
    *(u16x8*)&s1b[ob + 8] = h1;
  }
}

// ---------------- layer-2 linear (h[256] -> 20 outs per row) ----------------
// outputs: qs2[n][12] = {q2[0:5], skip2[0:5], pad2}; kv2[n][12] = {k2[0:5], v2[0:5], pad2}
__global__ __launch_bounds__(256) void lin2_kernel(const unsigned short* __restrict__ hb,
                                                   const float* __restrict__ w2t,
                                                   const float* __restrict__ bias2,
                                                   float* __restrict__ qs2, float* __restrict__ kv2) {
  __shared__ float ws[20 * 256];
  __shared__ float bs[20];
  for (int i = threadIdx.x; i < 20 * 256; i += 256) ws[i] = w2t[i];
  if (threadIdx.x < 20) bs[threadIdx.x] = bias2[threadIdx.x];
  __syncthreads();
  int w = threadIdx.x >> 6, l = threadIdx.x & 63;
  int n = blockIdx.x * 4 + w;
  if (n >= N_NODES) return;
  ushort4 hu = *(const ushort4*)&hb[(long)n * 256 + l * 4];
  float h0 = bf2f(hu.x), h1 = bf2f(hu.y), h2 = bf2f(hu.z), h3 = bf2f(hu.w);
  float myout = 0.f;
#pragma unroll
  for (int c = 0; c < 20; ++c) {
    float4 wv = *(const float4*)&ws[c * 256 + l * 4];
    float pp = h0 * wv.x + h1 * wv.y + h2 * wv.z + h3 * wv.w;
    pp += __shfl_xor(pp, 1);  pp += __shfl_xor(pp, 2);  pp += __shfl_xor(pp, 4);
    pp += __shfl_xor(pp, 8);  pp += __shfl_xor(pp, 16); pp += __shfl_xor(pp, 32);
    if (l == c) myout = pp + bs[c];
  }
  // c order: 0-4 q, 5-9 k, 10-14 v, 15-19 skip
  if (l < 5) qs2[(long)n * 12 + l] = myout;                 // q
  else if (l < 15) kv2[(long)n * 12 + (l - 5)] = myout;     // k,v
  else if (l < 20) qs2[(long)n * 12 + (l - 10)] = myout;    // skip
}

// ---------------- layer-2 fused attention (1 thread per node) ----------------
__global__ void agg2_kernel(const float* __restrict__ qs2, const float* __restrict__ kv2,
                            const int* __restrict__ offsets, const int* __restrict__ csr_src,
                            float* __restrict__ out) {
  int n = blockIdx.x * 256 + threadIdx.x;
  if (n >= N_NODES) return;
  const float* bn = &qs2[(long)n * 12];
  const float is5 = 0.4472135954999579f;  // 1/sqrt(5)
  float q[5], acc[5] = {0, 0, 0, 0, 0}, se = 0.f;
#pragma unroll
  for (int c = 0; c < 5; ++c) q[c] = bn[c] * is5;
  int i0 = offsets[n], i1 = offsets[n + 1];
  for (int i = i0; i < i1; ++i) {
    int s = csr_src[i];
    const float4* ps = (const float4*)&kv2[(long)s * 12];
    float4 A = ps[0], B = ps[1], C = ps[2];
    float lg = q[0] * A.x + q[1] * A.y + q[2] * A.z + q[3] * A.w + q[4] * B.x;
    float ee = __expf(lg);
    se += ee;
    acc[0] += ee * B.y; acc[1] += ee * B.z; acc[2] += ee * B.w;
    acc[3] += ee * C.x; acc[4] += ee * C.y;
  }
  float inv = 1.f / (se + 1e-16f);
#pragma unroll
  for (int c = 0; c < 5; ++c) out[(long)n * 5 + c] = acc[c] * inv + bn[5 + c];
}

// ---------------- launch ----------------
extern "C" void kernel_launch(void* const* d_in, const int* in_sizes, int n_in,
                              void* d_out, int out_size, void* d_ws, size_t ws_size,
                              hipStream_t stream) {
  (void)in_sizes; (void)n_in; (void)out_size; (void)ws_size;
  const float* x   = (const float*)d_in[0];
  const int* eidx  = (const int*)d_in[1];
  const int* esrc  = eidx;
  const int* edst  = eidx + N_EDGES;
  const float* Wq1 = (const float*)d_in[2];  const float* bq1 = (const float*)d_in[3];
  const float* Wk1 = (const float*)d_in[4];  const float* bk1 = (const float*)d_in[5];
  const float* Wv1 = (const float*)d_in[6];  const float* bv1 = (const float*)d_in[7];
  const float* Ws1 = (const float*)d_in[8];  const float* bs1 = (const float*)d_in[9];
  const float* Wq2 = (const float*)d_in[10]; const float* bq2 = (const float*)d_in[11];
  const float* Wk2 = (const float*)d_in[12]; const float* bk2 = (const float*)d_in[13];
  const float* Wv2 = (const float*)d_in[14]; const float* bv2 = (const float*)d_in[15];
  const float* Ws2 = (const float*)d_in[16]; const float* bs2 = (const float*)d_in[17];

  char* p = (char*)d_ws;
  auto take = [&](size_t bytes) { char* r = p; p += (bytes + 255) & ~(size_t)255; return r; };
  unsigned short* xb  = (unsigned short*)take((size_t)NPAD * 384 * 2);
  unsigned short* wbt = (unsigned short*)take((size_t)1024 * 384 * 2);
  float* bias1        = (float*)take(1024 * 4);
  unsigned short* qb  = (unsigned short*)take((size_t)NPAD * 256 * 2);
  unsigned char* kvb  = (unsigned char*)take((size_t)NPAD * 512);
  unsigned short* s1b = (unsigned short*)take((size_t)NPAD * 256 * 2);
  float* w2t          = (float*)take(20 * 256 * 4);
  float* bias2        = (float*)take(32 * 4);
  float* qs2          = (float*)take((size_t)NPAD * 12 * 4);
  float* kv2          = (float*)take((size_t)NPAD * 12 * 4);
  int* counts         = (int*)take((size_t)N_NODES * 4);
  int* offsets        = (int*)take((size_t)(N_NODES + 1) * 4);
  int* cursor         = (int*)take((size_t)N_NODES * 4);
  int* csr_src        = (int*)take((size_t)N_EDGES * 4);
  int* scan_tmp       = (int*)take((size_t)N_NODES * 4);
  int* scan_bsum      = (int*)take(256 * 4);
  int* scan_bbase     = (int*)take(256 * 4);

  hipMemsetAsync(counts, 0, (size_t)N_NODES * 4, stream);
  hist_kernel<<<(N_EDGES + 255) / 256, 256, 0, stream>>>(edst, counts, N_EDGES);
  scan1_kernel<<<SCAN_B, 256, 0, stream>>>(counts, scan_tmp, scan_bsum, N_NODES);
  scan2_kernel<<<1, 256, 0, stream>>>(scan_bsum, scan_bbase, SCAN_B);
  scan3_kernel<<<SCAN_B, 256, 0, stream>>>(scan_tmp, scan_bbase, offsets, cursor, N_NODES, N_EDGES);
  scatter_kernel<<<(N_EDGES + 255) / 256, 256, 0, stream>>>(esrc, edst, cursor, csr_src, N_EDGES);
  convert_x_kernel<<<(NPAD * 384 / 8 + 255) / 256, 256, 0, stream>>>(x, xb, N_NODES * 384, NPAD * 384);
  pack_w1_kernel<<<(1024 * 384 + 255) / 256, 256, 0, stream>>>(Wq1, Wk1, Wv1, Ws1, bq1, bk1, bv1, bs1, wbt, bias1);
  pack_w2_kernel<<<(20 * 256 + 255) / 256, 256, 0, stream>>>(Wq2, Wk2, Wv2, Ws2, bq2, bk2, bv2, bs2, w2t, bias2);
  gemm1_kernel<<<dim3(NPAD / 128, 4), 512, 0, stream>>>(xb, wbt, bias1, qb, kvb, s1b);
  agg1_kernel<<<(N_NODES + 3) / 4, 256, 0, stream>>>(qb, kvb, s1b, offsets, csr_src);
  lin2_kernel<<<(N_NODES + 3) / 4, 256, 0, stream>>>(s1b, w2t, bias2, qs2, kv2);
  agg2_kernel<<<(N_NODES + 255) / 256, 256, 0, stream>>>(qs2, kv2, offsets, csr_src, (float*)d_out);
}

// Round 5
// 279.737 us; speedup vs baseline: 1.4652x; 1.3231x over previous
//
#include <hip/hip_runtime.h>
#include <hip/hip_bf16.h>

#define N_NODES 50000
#define N_EDGES 800000
#define NPAD    50048   // 391*128
#define SCAN_B  196     // ceil(50000/256)

typedef __attribute__((ext_vector_type(8))) short bf16x8;
typedef __attribute__((ext_vector_type(8))) unsigned short u16x8;
typedef __attribute__((ext_vector_type(4))) float f32x4;

__device__ __forceinline__ unsigned short f2bf(float f) {
  union { float f; unsigned u; } x; x.f = f;
  unsigned r = x.u + 0x7fffu + ((x.u >> 16) & 1u);
  return (unsigned short)(r >> 16);
}
__device__ __forceinline__ float bf2f(unsigned short u) {
  union { unsigned u; float f; } x; x.u = ((unsigned)u) << 16;
  return x.f;
}
// biased i8, scale 16: b = clamp(round(v*16)+128, 0, 255); v = (b-128)/16
__device__ __forceinline__ unsigned char enc8(float v) {
  float t = fminf(fmaxf(fmaf(v, 16.f, 128.5f), 0.f), 255.f);
  return (unsigned char)(int)t;
}

// async global->LDS, 16B per lane (dest must be linear: base + lane*16)
__device__ __forceinline__ void gload16(const unsigned short* g, unsigned short* l) {
  __builtin_amdgcn_global_load_lds(
      (const __attribute__((address_space(1))) unsigned int*)g,
      (__attribute__((address_space(3))) unsigned int*)l, 16, 0, 0);
}

// ---------------- CSR build ----------------
__global__ void hist_kernel(const int* __restrict__ dst, int* __restrict__ counts, int E) {
  int e = blockIdx.x * 256 + threadIdx.x;
  if (e < E) atomicAdd(&counts[dst[e]], 1);
}

__global__ __launch_bounds__(256) void scan1_kernel(const int* __restrict__ counts,
                                                    int* __restrict__ tmp, int* __restrict__ bsum, int n) {
  __shared__ int sm[256];
  int i = blockIdx.x * 256 + threadIdx.x;
  int v = (i < n) ? counts[i] : 0;
  sm[threadIdx.x] = v;
  __syncthreads();
  for (int off = 1; off < 256; off <<= 1) {
    int t = (threadIdx.x >= off) ? sm[threadIdx.x - off] : 0;
    __syncthreads();
    sm[threadIdx.x] += t;
    __syncthreads();
  }
  if (i < n) tmp[i] = sm[threadIdx.x] - v;
  if (threadIdx.x == 255) bsum[blockIdx.x] = sm[255];
}

__global__ __launch_bounds__(256) void scan2_kernel(const int* __restrict__ bsum,
                                                    int* __restrict__ bbase, int nb) {
  __shared__ int sm[256];
  int v = (threadIdx.x < nb) ? bsum[threadIdx.x] : 0;
  sm[threadIdx.x] = v;
  __syncthreads();
  for (int off = 1; off < 256; off <<= 1) {
    int t = (threadIdx.x >= off) ? sm[threadIdx.x - off] : 0;
    __syncthreads();
    sm[threadIdx.x] += t;
    __syncthreads();
  }
  if (threadIdx.x < nb) bbase[threadIdx.x] = sm[threadIdx.x] - v;
}

__global__ __launch_bounds__(256) void scan3_kernel(const int* __restrict__ tmp,
                                                    const int* __restrict__ bbase,
                                                    int* __restrict__ offsets, int* __restrict__ cursor,
                                                    int n, int E) {
  int i = blockIdx.x * 256 + threadIdx.x;
  if (i < n) {
    int o = tmp[i] + bbase[blockIdx.x];
    offsets[i] = o;
    cursor[i] = o;
  }
  if (i == 0) offsets[n] = E;
}

__global__ void scatter_kernel(const int* __restrict__ src, const int* __restrict__ dst,
                               int* __restrict__ cursor, int* __restrict__ csr_src, int E) {
  int e = blockIdx.x * 256 + threadIdx.x;
  if (e < E) {
    int pos = atomicAdd(&cursor[dst[e]], 1);
    csr_src[pos] = src[e];
  }
}

// ---------------- packing / conversion ----------------
__global__ void convert_x_kernel(const float* __restrict__ x, unsigned short* __restrict__ xb,
                                 int total_real, int total_pad) {
  long i = ((long)blockIdx.x * 256 + threadIdx.x) * 8;
  if (i >= total_pad) return;
  u16x8 o;
  if (i < total_real) {
    float4 v0 = *(const float4*)&x[i];
    float4 v1 = *(const float4*)&x[i + 4];
    o[0] = (short)f2bf(v0.x); o[1] = (short)f2bf(v0.y);
    o[2] = (short)f2bf(v0.z); o[3] = (short)f2bf(v0.w);
    o[4] = (short)f2bf(v1.x); o[5] = (short)f2bf(v1.y);
    o[6] = (short)f2bf(v1.z); o[7] = (short)f2bf(v1.w);
  } else {
    o = (u16x8)0;
  }
  *(u16x8*)&xb[i] = o;
}

__global__ void pack_w1_kernel(const float* __restrict__ Wq, const float* __restrict__ Wk,
                               const float* __restrict__ Wv, const float* __restrict__ Ws,
                               const float* __restrict__ bq, const float* __restrict__ bk,
                               const float* __restrict__ bv, const float* __restrict__ bs_,
                               unsigned short* __restrict__ wbt, float* __restrict__ bias1) {
  int idx = blockIdx.x * 256 + threadIdx.x;
  if (idx >= 1024 * 384) return;
  int n = idx / 384, k = idx - n * 384;
  int blk = n >> 8, cc = n & 255;
  const float* W = (blk == 0) ? Wq : (blk == 1) ? Wk : (blk == 2) ? Wv : Ws;
  wbt[idx] = f2bf(W[(long)k * 256 + cc]);   // wbt[n][k] = W[k][cc]  (transposed)
  if (k == 0) {
    const float* b = (blk == 0) ? bq : (blk == 1) ? bk : (blk == 2) ? bv : bs_;
    bias1[n] = b[cc];
  }
}

// w2bt[c][p] (bf16, 32x256): K-dim p is in STORAGE order (the permutation the
// gemm1 epilogue applies within each 64-col block: p = base64 + lr*4 + nf,
// true channel = base64 + nf*16 + lr). c: 0-4 q, 5-9 k, 10-14 v, 15-19 skip.
__global__ void pack_w2_kernel(const float* __restrict__ Wq, const float* __restrict__ Wk,
                               const float* __restrict__ Wv, const float* __restrict__ Ws,
                               const float* __restrict__ bq, const float* __restrict__ bk,
                               const float* __restrict__ bv, const float* __restrict__ bs_,
                               unsigned short* __restrict__ w2bt, float* __restrict__ bias2) {
  int idx = blockIdx.x * 256 + threadIdx.x;
  if (idx >= 32 * 256) return;
  int c = idx >> 8, p = idx & 255;
  unsigned short o = 0;
  if (c < 20) {
    int blk = c / 5, cc = c - blk * 5;
    int tch = (p & 0xC0) + (p & 3) * 16 + ((p & 63) >> 2);   // inverse permutation
    const float* W = (blk == 0) ? Wq : (blk == 1) ? Wk : (blk == 2) ? Wv : Ws;
    o = f2bf(W[(long)tch * 5 + cc]);
    if (p == 0) {
      const float* b = (blk == 0) ? bq : (blk == 1) ? bk : (blk == 2) ? bv : bs_;
      bias2[c] = b[cc];
    }
  }
  w2bt[idx] = o;
}

// ---------------- layer-1 fused QKVS GEMM (bf16 MFMA, single-buffer) ----------------
// Y[NPAD][1024] = xb[NPAD][384] @ W[384][1024] + bias
// Outputs stored in PERMUTED channel order (per 64-block: pos = lr*4+nf) so each
// lane stores its 4 nf-values contiguously -> full-cacheline coalesced stores.
// y=0 -> q bf16 [N][256]; y=1 -> k i8 kvb[n*512+pos]; y=2 -> v i8 kvb[n*512+256+pos];
// y=3 -> skip bf16 [N][256]. q/k share perm (dot invariant); v/s1/h share perm;
// lin2 undoes it via pack_w2.
__global__ __launch_bounds__(512) void gemm1_kernel(
    const unsigned short* __restrict__ xb, const unsigned short* __restrict__ wbt,
    const float* __restrict__ bias,
    unsigned short* __restrict__ qb, unsigned char* __restrict__ kvb,
    unsigned short* __restrict__ s1b) {
  __shared__ unsigned short As[128 * 32];   // 8 KB
  __shared__ unsigned short Bs[256 * 32];   // 16 KB
  int tid = threadIdx.x;
  long m0 = (long)blockIdx.x * 128;
  int n0 = blockIdx.y * 256;
  int w = tid >> 6, l = tid & 63;
  int wr = (w >> 2) * 64, wc = (w & 3) * 64;
  int lr = l & 15, c0 = l >> 4;
  int sw = (lr ^ (lr >> 2)) & 3;
  int swoff = (c0 ^ sw) * 8;                // swizzled fragment chunk, loop-invariant
  f32x4 acc[4][4] = {};
  int rs = tid >> 2, ss = tid & 3;
  int fa = (rs ^ (rs >> 2)) & 3;
  int fb1 = ((rs + 128) ^ ((rs + 128) >> 2)) & 3;
  const unsigned short* gA  = xb + (m0 + rs) * 384 + ((ss ^ fa) * 8);
  const unsigned short* gB0 = wbt + (long)(n0 + rs) * 384 + ((ss ^ fa) * 8);
  const unsigned short* gB1 = wbt + (long)(n0 + rs + 128) * 384 + ((ss ^ fb1) * 8);
  for (int kt = 0; kt < 12; ++kt) {
    int ko = kt * 32;
    __syncthreads();   // previous tile consumed
    gload16(gA + ko, &As[tid * 8]);
    gload16(gB0 + ko, &Bs[tid * 8]);
    gload16(gB1 + ko, &Bs[4096 + tid * 8]);
    __syncthreads();   // drains vmcnt: tile ready
    bf16x8 af[4], bfv[4];
#pragma unroll
    for (int mf = 0; mf < 4; ++mf) af[mf] = *(const bf16x8*)&As[(wr + mf * 16 + lr) * 32 + swoff];
#pragma unroll
    for (int nf = 0; nf < 4; ++nf) bfv[nf] = *(const bf16x8*)&Bs[(wc + nf * 16 + lr) * 32 + swoff];
#pragma unroll
    for (int mf = 0; mf < 4; ++mf)
#pragma unroll
      for (int nf = 0; nf < 4; ++nf)
        acc[mf][nf] = __builtin_amdgcn_mfma_f32_16x16x32_bf16(af[mf], bfv[nf], acc[mf][nf], 0, 0, 0);
  }
  int y = blockIdx.y;
  float bv[4];
#pragma unroll
  for (int nf = 0; nf < 4; ++nf) bv[nf] = bias[n0 + wc + nf * 16 + lr];
  int pos = wc + lr * 4;
#pragma unroll
  for (int mf = 0; mf < 4; ++mf) {
#pragma unroll
    for (int i = 0; i < 4; ++i) {
      long row = m0 + wr + mf * 16 + c0 * 4 + i;
      float v0 = acc[mf][0][i] + bv[0];
      float v1 = acc[mf][1][i] + bv[1];
      float v2 = acc[mf][2][i] + bv[2];
      float v3 = acc[mf][3][i] + bv[3];
      if (y == 0 || y == 3) {
        ushort4 st;
        st.x = f2bf(v0); st.y = f2bf(v1); st.z = f2bf(v2); st.w = f2bf(v3);
        unsigned short* dst = (y == 0) ? qb : s1b;
        *(ushort4*)&dst[row * 256 + pos] = st;
      } else {
        uchar4 st;
        st.x = enc8(v0); st.y = enc8(v1); st.z = enc8(v2); st.w = enc8(v3);
        *(uchar4*)&kvb[row * 512 + ((y == 1) ? 0 : 256) + pos] = st;
      }
    }
  }
}

// ---------------- layer-1 fused attention aggregation (i8 kv) ----------------
// one wave per node; 16-lane group g handles edge i+g; lane owns 16 channels.
// kv record: 512 B, k bytes 0-255, v bytes 256-511; b = v*16+128.
// logit = sum q'*b - 128*sum q'  (q' = q/(8*16)); v_attn = (sum(e*b)/sum(e))/16 - 8.
// (channel order is the gemm's permuted storage order -- consistent everywhere)
__global__ __launch_bounds__(256) void agg1_kernel(
    const unsigned short* __restrict__ qb, const unsigned char* __restrict__ kvb,
    unsigned short* s1b,
    const int* __restrict__ offsets, const int* __restrict__ csr_src) {
  int w = threadIdx.x >> 6, l = threadIdx.x & 63;
  int n = blockIdx.x * 4 + w;
  if (n >= N_NODES) return;
  int g = l >> 4;            // edge slot 0..3
  int sub = l & 15;          // channel block (head = sub>>2)
  float qf[16];
  float qs = 0.f;
  {
    const unsigned short* qrow = qb + (long)n * 256 + sub * 16;
    u16x8 q0 = *(const u16x8*)qrow;
    u16x8 q1 = *(const u16x8*)(qrow + 8);
#pragma unroll
    for (int j = 0; j < 8; ++j) {
      qf[j] = bf2f((unsigned short)q0[j]) * 0.0078125f;       // 1/(8*16)
      qf[8 + j] = bf2f((unsigned short)q1[j]) * 0.0078125f;
    }
#pragma unroll
    for (int j = 0; j < 16; ++j) qs += qf[j];
    qs += __shfl_xor(qs, 1); qs += __shfl_xor(qs, 2);         // head-level sum
  }
  float pc = 128.f * qs;
  float acc[16] = {};
  float se = 0.f;
  int i0 = offsets[n], i1 = offsets[n + 1];
#define DOT4(P, W, B) \
  P = fmaf(qf[(B) + 0], (float)((W) & 0xffu), P); \
  P = fmaf(qf[(B) + 1], (float)(((W) >> 8) & 0xffu), P); \
  P = fmaf(qf[(B) + 2], (float)(((W) >> 16) & 0xffu), P); \
  P = fmaf(qf[(B) + 3], (float)((W) >> 24), P);
#define VACC(E, W, B) \
  acc[(B) + 0] = fmaf(E, (float)((W) & 0xffu), acc[(B) + 0]); \
  acc[(B) + 1] = fmaf(E, (float)(((W) >> 8) & 0xffu), acc[(B) + 1]); \
  acc[(B) + 2] = fmaf(E, (float)(((W) >> 16) & 0xffu), acc[(B) + 2]); \
  acc[(B) + 3] = fmaf(E, (float)((W) >> 24), acc[(B) + 3]);
  for (int i = i0; i < i1; i += 8) {
    int ia = i + g, ib = i + 4 + g;
    int sa = csr_src[ia < i1 ? ia : i1 - 1];
    int sb = csr_src[ib < i1 ? ib : i1 - 1];
    const uint4* pa = (const uint4*)(kvb + (long)sa * 512 + sub * 16);
    const uint4* pb = (const uint4*)(kvb + (long)sb * 512 + sub * 16);
    uint4 ka = pa[0], va = pa[16];     // +16 uint4 = +256 B
    uint4 kw = pb[0], vw = pb[16];
    float pa_ = 0.f, pb_ = 0.f;
    DOT4(pa_, ka.x, 0) DOT4(pa_, ka.y, 4) DOT4(pa_, ka.z, 8) DOT4(pa_, ka.w, 12)
    DOT4(pb_, kw.x, 0) DOT4(pb_, kw.y, 4) DOT4(pb_, kw.z, 8) DOT4(pb_, kw.w, 12)
    pa_ += __shfl_xor(pa_, 1); pa_ += __shfl_xor(pa_, 2);
    pb_ += __shfl_xor(pb_, 1); pb_ += __shfl_xor(pb_, 2);
    float ea = (ia < i1) ? __expf(pa_ - pc) : 0.f;
    float eb = (ib < i1) ? __expf(pb_ - pc) : 0.f;
    se += ea + eb;
    VACC(ea, va.x, 0) VACC(ea, va.y, 4) VACC(ea, va.z, 8) VACC(ea, va.w, 12)
    VACC(eb, vw.x, 0) VACC(eb, vw.y, 4) VACC(eb, vw.z, 8) VACC(eb, vw.w, 12)
  }
#undef DOT4
#undef VACC
#pragma unroll
  for (int j = 0; j < 16; ++j) {
    acc[j] += __shfl_xor(acc[j], 16);
    acc[j] += __shfl_xor(acc[j], 32);
  }
  se += __shfl_xor(se, 16);
  se += __shfl_xor(se, 32);
  if (g == 0) {
    float inv = (se > 0.f) ? 1.0f / se : 0.f;
    float bias = (se > 0.f) ? -8.0f : 0.f;   // deg-0 node: attn out = 0
    long ob = (long)n * 256 + sub * 16;
    u16x8 sv0 = *(const u16x8*)&s1b[ob];
    u16x8 sv1 = *(const u16x8*)&s1b[ob + 8];
    u16x8 h0, h1;
#pragma unroll
    for (int j = 0; j < 8; ++j) {
      float v0 = fmaf(acc[j] * inv, 0.0625f, bias);
      float v1 = fmaf(acc[8 + j] * inv, 0.0625f, bias);
      h0[j] = (short)f2bf(fmaxf(v0 + bf2f((unsigned short)sv0[j]), 0.f));
      h1[j] = (short)f2bf(fmaxf(v1 + bf2f((unsigned short)sv1[j]), 0.f));
    }
    *(u16x8*)&s1b[ob] = h0;
    *(u16x8*)&s1b[ob + 8] = h1;
  }
}

// ---------------- layer-2 linear via MFMA: [NPAD x 256] @ [256 x 32] ----------------
// h (bf16, permuted channels) x w2bt (undoes permutation). 256 thr = 4 waves,
// each wave 32 rows x 32 cols; block = 128 rows. B staged in padded LDS [32][264].
__global__ __launch_bounds__(256) void lin2_kernel(const unsigned short* __restrict__ hb,
                                                   const unsigned short* __restrict__ w2bt,
                                                   const float* __restrict__ bias2,
                                                   float* __restrict__ qs2, float* __restrict__ kv2) {
  __shared__ unsigned short Bs2[32 * 264];
  __shared__ float bsh[32];
  for (int i = threadIdx.x; i < 32 * 32; i += 256) {
    int r = i >> 5, cc = i & 31;
    *(u16x8*)&Bs2[r * 264 + cc * 8] = *(const u16x8*)&w2bt[r * 256 + cc * 8];
  }
  if (threadIdx.x < 32) bsh[threadIdx.x] = (threadIdx.x < 20) ? bias2[threadIdx.x] : 0.f;
  __syncthreads();
  int w = threadIdx.x >> 6, l = threadIdx.x & 63;
  long row0 = (long)blockIdx.x * 128 + w * 32;
  int lr = l & 15, c0 = l >> 4;
  f32x4 acc[2][2] = {};
  for (int kk = 0; kk < 8; ++kk) {
    int koff = kk * 32 + c0 * 8;
    bf16x8 af[2], bfv[2];
    af[0] = *(const bf16x8*)&hb[(row0 + lr) * 256 + koff];
    af[1] = *(const bf16x8*)&hb[(row0 + 16 + lr) * 256 + koff];
    bfv[0] = *(const bf16x8*)&Bs2[lr * 264 + koff];
    bfv[1] = *(const bf16x8*)&Bs2[(16 + lr) * 264 + koff];
#pragma unroll
    for (int mf = 0; mf < 2; ++mf)
#pragma unroll
      for (int nf = 0; nf < 2; ++nf)
        acc[mf][nf] = __builtin_amdgcn_mfma_f32_16x16x32_bf16(af[mf], bfv[nf], acc[mf][nf], 0, 0, 0);
  }
  // c order: 0-4 q, 5-9 k, 10-14 v, 15-19 skip
#pragma unroll
  for (int mf = 0; mf < 2; ++mf) {
#pragma unroll
    for (int nf = 0; nf < 2; ++nf) {
      int col = nf * 16 + lr;
#pragma unroll
      for (int i = 0; i < 4; ++i) {
        long n = row0 + mf * 16 + c0 * 4 + i;
        float v = acc[mf][nf][i] + bsh[col];
        if (col < 5) qs2[n * 12 + col] = v;
        else if (col < 15) kv2[n * 12 + (col - 5)] = v;
        else if (col < 20) qs2[n * 12 + (col - 10)] = v;
      }
    }
  }
}

// ---------------- layer-2 fused attention (1 thread per node) ----------------
__global__ void agg2_kernel(const float* __restrict__ qs2, const float* __restrict__ kv2,
                            const int* __restrict__ offsets, const int* __restrict__ csr_src,
                            float* __restrict__ out) {
  int n = blockIdx.x * 256 + threadIdx.x;
  if (n >= N_NODES) return;
  const float* bn = &qs2[(long)n * 12];
  const float is5 = 0.4472135954999579f;  // 1/sqrt(5)
  float q[5], acc[5] = {0, 0, 0, 0, 0}, se = 0.f;
#pragma unroll
  for (int c = 0; c < 5; ++c) q[c] = bn[c] * is5;
  int i0 = offsets[n], i1 = offsets[n + 1];
  for (int i = i0; i < i1; ++i) {
    int s = csr_src[i];
    const float4* ps = (const float4*)&kv2[(long)s * 12];
    float4 A = ps[0], B = ps[1], C = ps[2];
    float lg = q[0] * A.x + q[1] * A.y + q[2] * A.z + q[3] * A.w + q[4] * B.x;
    float ee = __expf(lg);
    se += ee;
    acc[0] += ee * B.y; acc[1] += ee * B.z; acc[2] += ee * B.w;
    acc[3] += ee * C.x; acc[4] += ee * C.y;
  }
  float inv = 1.f / (se + 1e-16f);
#pragma unroll
  for (int c = 0; c < 5; ++c) out[(long)n * 5 + c] = acc[c] * inv + bn[5 + c];
}

// ---------------- launch ----------------
extern "C" void kernel_launch(void* const* d_in, const int* in_sizes, int n_in,
                              void* d_out, int out_size, void* d_ws, size_t ws_size,
                              hipStream_t stream) {
  (void)in_sizes; (void)n_in; (void)out_size; (void)ws_size;
  const float* x   = (const float*)d_in[0];
  const int* eidx  = (const int*)d_in[1];
  const int* esrc  = eidx;
  const int* edst  = eidx + N_EDGES;
  const float* Wq1 = (const float*)d_in[2];  const float* bq1 = (const float*)d_in[3];
  const float* Wk1 = (const float*)d_in[4];  const float* bk1 = (const float*)d_in[5];
  const float* Wv1 = (const float*)d_in[6];  const float* bv1 = (const float*)d_in[7];
  const float* Ws1 = (const float*)d_in[8];  const float* bs1 = (const float*)d_in[9];
  const float* Wq2 = (const float*)d_in[10]; const float* bq2 = (const float*)d_in[11];
  const float* Wk2 = (const float*)d_in[12]; const float* bk2 = (const float*)d_in[13];
  const float* Wv2 = (const float*)d_in[14]; const float* bv2 = (const float*)d_in[15];
  const float* Ws2 = (const float*)d_in[16]; const float* bs2 = (const float*)d_in[17];

  char* p = (char*)d_ws;
  auto take = [&](size_t bytes) { char* r = p; p += (bytes + 255) & ~(size_t)255; return r; };
  unsigned short* xb  = (unsigned short*)take((size_t)NPAD * 384 * 2);
  unsigned short* wbt = (unsigned short*)take((size_t)1024 * 384 * 2);
  float* bias1        = (float*)take(1024 * 4);
  unsigned short* qb  = (unsigned short*)take((size_t)NPAD * 256 * 2);
  unsigned char* kvb  = (unsigned char*)take((size_t)NPAD * 512);
  unsigned short* s1b = (unsigned short*)take((size_t)NPAD * 256 * 2);
  unsigned short* w2bt = (unsigned short*)take(32 * 256 * 2);
  float* bias2        = (float*)take(32 * 4);
  float* qs2          = (float*)take((size_t)NPAD * 12 * 4);
  float* kv2          = (float*)take((size_t)NPAD * 12 * 4);
  int* counts         = (int*)take((size_t)N_NODES * 4);
  int* offsets        = (int*)take((size_t)(N_NODES + 1) * 4);
  int* cursor         = (int*)take((size_t)N_NODES * 4);
  int* csr_src        = (int*)take((size_t)N_EDGES * 4);
  int* scan_tmp       = (int*)take((size_t)N_NODES * 4);
  int* scan_bsum      = (int*)take(256 * 4);
  int* scan_bbase     = (int*)take(256 * 4);

  hipMemsetAsync(counts, 0, (size_t)N_NODES * 4, stream);
  hist_kernel<<<(N_EDGES + 255) / 256, 256, 0, stream>>>(edst, counts, N_EDGES);
  scan1_kernel<<<SCAN_B, 256, 0, stream>>>(counts, scan_tmp, scan_bsum, N_NODES);
  scan2_kernel<<<1, 256, 0, stream>>>(scan_bsum, scan_bbase, SCAN_B);
  scan3_kernel<<<SCAN_B, 256, 0, stream>>>(scan_tmp, scan_bbase, offsets, cursor, N_NODES, N_EDGES);
  scatter_kernel<<<(N_EDGES + 255) / 256, 256, 0, stream>>>(esrc, edst, cursor, csr_src, N_EDGES);
  convert_x_kernel<<<(NPAD * 384 / 8 + 255) / 256, 256, 0, stream>>>(x, xb, N_NODES * 384, NPAD * 384);
  pack_w1_kernel<<<(1024 * 384 + 255) / 256, 256, 0, stream>>>(Wq1, Wk1, Wv1, Ws1, bq1, bk1, bv1, bs1, wbt, bias1);
  pack_w2_kernel<<<(32 * 256 + 255) / 256, 256, 0, stream>>>(Wq2, Wk2, Wv2, Ws2, bq2, bk2, bv2, bs2, w2bt, bias2);
  gemm1_kernel<<<dim3(NPAD / 128, 4), 512, 0, stream>>>(xb, wbt, bias1, qb, kvb, s1b);
  agg1_kernel<<<(N_NODES + 3) / 4, 256, 0, stream>>>(qb, kvb, s1b, offsets, csr_src);
  lin2_kernel<<<NPAD / 128, 256, 0, stream>>>(s1b, w2bt, bias2, qs2, kv2);
  agg2_kernel<<<(N_NODES + 255) / 256, 256, 0, stream>>>(qs2, kv2, offsets, csr_src, (float*)d_out);
}

// Round 6
// 279.704 us; speedup vs baseline: 1.4654x; 1.0001x over previous
//
#include <hip/hip_runtime.h>
#include <hip/hip_bf16.h>

#define N_NODES 50000
#define N_EDGES 800000
#define NPAD    50048   // 391*128
#define SCAN_B  196     // ceil(50000/256)

typedef __attribute__((ext_vector_type(8))) short bf16x8;
typedef __attribute__((ext_vector_type(8))) unsigned short u16x8;
typedef __attribute__((ext_vector_type(4))) float f32x4;

__device__ __forceinline__ unsigned short f2bf(float f) {
  union { float f; unsigned u; } x; x.f = f;
  unsigned r = x.u + 0x7fffu + ((x.u >> 16) & 1u);
  return (unsigned short)(r >> 16);
}
__device__ __forceinline__ float bf2f(unsigned short u) {
  union { unsigned u; float f; } x; x.u = ((unsigned)u) << 16;
  return x.f;
}
// v: biased u8, scale 16: b = clamp(round(v*16)+128, 0,255); v = (b-128)/16
__device__ __forceinline__ unsigned char enc8v(float v) {
  float t = fminf(fmaxf(fmaf(v, 16.f, 128.5f), 0.f), 255.f);
  return (unsigned char)(int)t;
}
// k: signed i8, scale 16
__device__ __forceinline__ char enc8k(float v) {
  float t = fminf(fmaxf(v * 16.f, -127.f), 127.f);
  return (char)(int)floorf(t + 0.5f);
}
// q: signed i8, scale 24 (clip at |q|>5.29 -- ~1 element in 12.8M)
__device__ __forceinline__ char enc8q(float v) {
  float t = fminf(fmaxf(v * 24.f, -127.f), 127.f);
  return (char)(int)floorf(t + 0.5f);
}

__device__ __forceinline__ int dot4i8(int a, int b, int c) {
#if __has_builtin(__builtin_amdgcn_sdot4)
  return __builtin_amdgcn_sdot4(a, b, c, false);
#else
  int r = c;
  r += (int)(char)(a) * (int)(char)(b);
  r += (int)(char)(a >> 8) * (int)(char)(b >> 8);
  r += (int)(char)(a >> 16) * (int)(char)(b >> 16);
  r += (int)(char)(a >> 24) * (int)(char)(b >> 24);
  return r;
#endif
}

// async global->LDS, 16B per lane (dest must be linear: base + lane*16)
__device__ __forceinline__ void gload16(const unsigned short* g, unsigned short* l) {
  __builtin_amdgcn_global_load_lds(
      (const __attribute__((address_space(1))) unsigned int*)g,
      (__attribute__((address_space(3))) unsigned int*)l, 16, 0, 0);
}

// ---------------- CSR build ----------------
__global__ void hist_kernel(const int* __restrict__ dst, int* __restrict__ counts, int E) {
  int e = blockIdx.x * 256 + threadIdx.x;
  if (e < E) atomicAdd(&counts[dst[e]], 1);
}

__global__ __launch_bounds__(256) void scan1_kernel(const int* __restrict__ counts,
                                                    int* __restrict__ tmp, int* __restrict__ bsum, int n) {
  __shared__ int sm[256];
  int i = blockIdx.x * 256 + threadIdx.x;
  int v = (i < n) ? counts[i] : 0;
  sm[threadIdx.x] = v;
  __syncthreads();
  for (int off = 1; off < 256; off <<= 1) {
    int t = (threadIdx.x >= off) ? sm[threadIdx.x - off] : 0;
    __syncthreads();
    sm[threadIdx.x] += t;
    __syncthreads();
  }
  if (i < n) tmp[i] = sm[threadIdx.x] - v;
  if (threadIdx.x == 255) bsum[blockIdx.x] = sm[255];
}

__global__ __launch_bounds__(256) void scan2_kernel(const int* __restrict__ bsum,
                                                    int* __restrict__ bbase, int nb) {
  __shared__ int sm[256];
  int v = (threadIdx.x < nb) ? bsum[threadIdx.x] : 0;
  sm[threadIdx.x] = v;
  __syncthreads();
  for (int off = 1; off < 256; off <<= 1) {
    int t = (threadIdx.x >= off) ? sm[threadIdx.x - off] : 0;
    __syncthreads();
    sm[threadIdx.x] += t;
    __syncthreads();
  }
  if (threadIdx.x < nb) bbase[threadIdx.x] = sm[threadIdx.x] - v;
}

__global__ __launch_bounds__(256) void scan3_kernel(const int* __restrict__ tmp,
                                                    const int* __restrict__ bbase,
                                                    int* __restrict__ offsets, int* __restrict__ cursor,
                                                    int n, int E) {
  int i = blockIdx.x * 256 + threadIdx.x;
  if (i < n) {
    int o = tmp[i] + bbase[blockIdx.x];
    offsets[i] = o;
    cursor[i] = o;
  }
  if (i == 0) offsets[n] = E;
}

__global__ void scatter_kernel(const int* __restrict__ src, const int* __restrict__ dst,
                               int* __restrict__ cursor, int* __restrict__ csr_src, int E) {
  int e = blockIdx.x * 256 + threadIdx.x;
  if (e < E) {
    int pos = atomicAdd(&cursor[dst[e]], 1);
    csr_src[pos] = src[e];
  }
}

// ---------------- packing / conversion ----------------
__global__ void convert_x_kernel(const float* __restrict__ x, unsigned short* __restrict__ xb,
                                 int total_real, int total_pad) {
  long i = ((long)blockIdx.x * 256 + threadIdx.x) * 8;
  if (i >= total_pad) return;
  u16x8 o;
  if (i < total_real) {
    float4 v0 = *(const float4*)&x[i];
    float4 v1 = *(const float4*)&x[i + 4];
    o[0] = (short)f2bf(v0.x); o[1] = (short)f2bf(v0.y);
    o[2] = (short)f2bf(v0.z); o[3] = (short)f2bf(v0.w);
    o[4] = (short)f2bf(v1.x); o[5] = (short)f2bf(v1.y);
    o[6] = (short)f2bf(v1.z); o[7] = (short)f2bf(v1.w);
  } else {
    o = (u16x8)0;
  }
  *(u16x8*)&xb[i] = o;
}

__global__ void pack_w1_kernel(const float* __restrict__ Wq, const float* __restrict__ Wk,
                               const float* __restrict__ Wv, const float* __restrict__ Ws,
                               const float* __restrict__ bq, const float* __restrict__ bk,
                               const float* __restrict__ bv, const float* __restrict__ bs_,
                               unsigned short* __restrict__ wbt, float* __restrict__ bias1) {
  int idx = blockIdx.x * 256 + threadIdx.x;
  if (idx >= 1024 * 384) return;
  int n = idx / 384, k = idx - n * 384;
  int blk = n >> 8, cc = n & 255;
  const float* W = (blk == 0) ? Wq : (blk == 1) ? Wk : (blk == 2) ? Wv : Ws;
  wbt[idx] = f2bf(W[(long)k * 256 + cc]);   // wbt[n][k] = W[k][cc]  (transposed)
  if (k == 0) {
    const float* b = (blk == 0) ? bq : (blk == 1) ? bk : (blk == 2) ? bv : bs_;
    bias1[n] = b[cc];
  }
}

// w2bt[c][p] (bf16, 32x256): K-dim p in STORAGE order (perm: p = base64 + lr*4 + nf,
// true channel = base64 + nf*16 + lr). c: 0-4 q, 5-9 k, 10-14 v, 15-19 skip.
__global__ void pack_w2_kernel(const float* __restrict__ Wq, const float* __restrict__ Wk,
                               const float* __restrict__ Wv, const float* __restrict__ Ws,
                               const float* __restrict__ bq, const float* __restrict__ bk,
                               const float* __restrict__ bv, const float* __restrict__ bs_,
                               unsigned short* __restrict__ w2bt, float* __restrict__ bias2) {
  int idx = blockIdx.x * 256 + threadIdx.x;
  if (idx >= 32 * 256) return;
  int c = idx >> 8, p = idx & 255;
  unsigned short o = 0;
  if (c < 20) {
    int blk = c / 5, cc = c - blk * 5;
    int tch = (p & 0xC0) + (p & 3) * 16 + ((p & 63) >> 2);   // inverse permutation
    const float* W = (blk == 0) ? Wq : (blk == 1) ? Wk : (blk == 2) ? Wv : Ws;
    o = f2bf(W[(long)tch * 5 + cc]);
    if (p == 0) {
      const float* b = (blk == 0) ? bq : (blk == 1) ? bk : (blk == 2) ? bv : bs_;
      bias2[c] = b[cc];
    }
  }
  w2bt[idx] = o;
}

// ---------------- layer-1 fused QKVS GEMM (bf16 MFMA, 2-phase dbuf) ----------------
// Y[NPAD][1024] = xb[NPAD][384] @ W[384][1024] + bias, permuted channel order.
// y=0 -> q i8(scale24) qb8[n][256]; y=1 -> k i8(scale16) kvb[n*512+pos];
// y=2 -> v u8-biased kvb[n*512+256+pos]; y=3 -> skip bf16 s1b[n][256].
// 1D grid with XCD-grouping: 4 N-blocks sharing an A-panel get bids == same mod 8
// so they land on one XCD and A re-reads hit that XCD's L2.
__global__ __launch_bounds__(512) void gemm1_kernel(
    const unsigned short* __restrict__ xb, const unsigned short* __restrict__ wbt,
    const float* __restrict__ bias,
    char* __restrict__ qb8, unsigned char* __restrict__ kvb,
    unsigned short* __restrict__ s1b) {
  __shared__ unsigned short As[2][128 * 32];   // 2 x 8 KB
  __shared__ unsigned short Bs[2][256 * 32];   // 2 x 16 KB
  int bid = blockIdx.x;
  int grp = bid >> 5, bl = bid & 31;
  int mx = grp * 8 + (bl & 7);
  int y = bl >> 3;
  if (mx >= NPAD / 128) return;   // uniform per block
  int tid = threadIdx.x;
  long m0 = (long)mx * 128;
  int n0 = y * 256;
  int w = tid >> 6, l = tid & 63;
  int wr = (w >> 2) * 64, wc = (w & 3) * 64;
  int lr = l & 15, c0 = l >> 4;
  int sw = (lr ^ (lr >> 2)) & 3;
  int swoff = (c0 ^ sw) * 8;                // swizzled fragment chunk, loop-invariant
  f32x4 acc[4][4] = {};
  int rs = tid >> 2, ss = tid & 3;
  int fa = (rs ^ (rs >> 2)) & 3;
  int fb1 = ((rs + 128) ^ ((rs + 128) >> 2)) & 3;
  const unsigned short* gA  = xb + (m0 + rs) * 384 + ((ss ^ fa) * 8);
  const unsigned short* gB0 = wbt + (long)(n0 + rs) * 384 + ((ss ^ fa) * 8);
  const unsigned short* gB1 = wbt + (long)(n0 + rs + 128) * 384 + ((ss ^ fb1) * 8);
  // prologue: stage tile 0 into buf 0
  gload16(gA, &As[0][tid * 8]);
  gload16(gB0, &Bs[0][tid * 8]);
  gload16(gB1, &Bs[0][4096 + tid * 8]);
  __syncthreads();
  for (int kt = 0; kt < 12; ++kt) {
    int b = kt & 1;
    if (kt < 11) {                           // stage next tile while computing
      int ko = (kt + 1) * 32;
      gload16(gA + ko, &As[b ^ 1][tid * 8]);
      gload16(gB0 + ko, &Bs[b ^ 1][tid * 8]);
      gload16(gB1 + ko, &Bs[b ^ 1][4096 + tid * 8]);
    }
    bf16x8 af[4], bfv[4];
#pragma unroll
    for (int mf = 0; mf < 4; ++mf) af[mf] = *(const bf16x8*)&As[b][(wr + mf * 16 + lr) * 32 + swoff];
#pragma unroll
    for (int nf = 0; nf < 4; ++nf) bfv[nf] = *(const bf16x8*)&Bs[b][(wc + nf * 16 + lr) * 32 + swoff];
#pragma unroll
    for (int mf = 0; mf < 4; ++mf)
#pragma unroll
      for (int nf = 0; nf < 4; ++nf)
        acc[mf][nf] = __builtin_amdgcn_mfma_f32_16x16x32_bf16(af[mf], bfv[nf], acc[mf][nf], 0, 0, 0);
    __syncthreads();                         // next tile staged + buf b consumed
  }
  float bv[4];
#pragma unroll
  for (int nf = 0; nf < 4; ++nf) bv[nf] = bias[n0 + wc + nf * 16 + lr];
  int pos = wc + lr * 4;
#pragma unroll
  for (int mf = 0; mf < 4; ++mf) {
#pragma unroll
    for (int i = 0; i < 4; ++i) {
      long row = m0 + wr + mf * 16 + c0 * 4 + i;
      float v0 = acc[mf][0][i] + bv[0];
      float v1 = acc[mf][1][i] + bv[1];
      float v2 = acc[mf][2][i] + bv[2];
      float v3 = acc[mf][3][i] + bv[3];
      if (y == 0) {
        char4 st; st.x = enc8q(v0); st.y = enc8q(v1); st.z = enc8q(v2); st.w = enc8q(v3);
        *(char4*)&qb8[row * 256 + pos] = st;
      } else if (y == 1) {
        char4 st; st.x = enc8k(v0); st.y = enc8k(v1); st.z = enc8k(v2); st.w = enc8k(v3);
        *(char4*)&kvb[row * 512 + pos] = st;
      } else if (y == 2) {
        uchar4 st; st.x = enc8v(v0); st.y = enc8v(v1); st.z = enc8v(v2); st.w = enc8v(v3);
        *(uchar4*)&kvb[row * 512 + 256 + pos] = st;
      } else {
        ushort4 st; st.x = f2bf(v0); st.y = f2bf(v1); st.z = f2bf(v2); st.w = f2bf(v3);
        *(ushort4*)&s1b[row * 256 + pos] = st;
      }
    }
  }
}

// ---------------- layer-1 fused attention aggregation (i8 kv, sdot4) ----------------
// grid-stride; one wave per node; 16-lane group g = edge slot; lane owns 16 channels.
// logit = sdot4(q8,k8)/3072 (q scale 24, k scale 16, /8 attn scale).
// v biased-u8: out = (sum(e*b)/sum(e))/16 - 8.
__global__ __launch_bounds__(256) void agg1_kernel(
    const char* __restrict__ qb8, const unsigned char* __restrict__ kvb,
    unsigned short* s1b,
    const int* __restrict__ offsets, const int* __restrict__ csr_src) {
  int w = threadIdx.x >> 6, l = threadIdx.x & 63;
  int g = l >> 4;            // edge slot 0..3
  int sub = l & 15;          // channel block (head = sub>>2)
  for (int n = blockIdx.x * 4 + w; n < N_NODES; n += gridDim.x * 4) {
    int4 qi = *(const int4*)&qb8[(long)n * 256 + sub * 16];
    float acc[16] = {};
    float se = 0.f;
    int i0 = offsets[n], i1 = offsets[n + 1];
#define VACC(E, W, B) \
    acc[(B) + 0] = fmaf(E, (float)((W) & 0xffu), acc[(B) + 0]); \
    acc[(B) + 1] = fmaf(E, (float)(((W) >> 8) & 0xffu), acc[(B) + 1]); \
    acc[(B) + 2] = fmaf(E, (float)(((W) >> 16) & 0xffu), acc[(B) + 2]); \
    acc[(B) + 3] = fmaf(E, (float)((W) >> 24), acc[(B) + 3]);
    for (int i = i0; i < i1; i += 8) {
      int ia = i + g, ib = i + 4 + g;
      int sa = csr_src[ia < i1 ? ia : i1 - 1];
      int sb = csr_src[ib < i1 ? ib : i1 - 1];
      const char* ba = (const char*)kvb + (long)sa * 512 + sub * 16;
      const char* bb = (const char*)kvb + (long)sb * 512 + sub * 16;
      int4 ka = *(const int4*)ba;
      int4 kw = *(const int4*)bb;
      uint4 va = *(const uint4*)(ba + 256);
      uint4 vw = *(const uint4*)(bb + 256);
      int da = 0, db = 0;
      da = dot4i8(qi.x, ka.x, da); da = dot4i8(qi.y, ka.y, da);
      da = dot4i8(qi.z, ka.z, da); da = dot4i8(qi.w, ka.w, da);
      db = dot4i8(qi.x, kw.x, db); db = dot4i8(qi.y, kw.y, db);
      db = dot4i8(qi.z, kw.z, db); db = dot4i8(qi.w, kw.w, db);
      da += __shfl_xor(da, 1); da += __shfl_xor(da, 2);
      db += __shfl_xor(db, 1); db += __shfl_xor(db, 2);
      float ea = (ia < i1) ? __expf((float)da * (1.f / 3072.f)) : 0.f;
      float eb = (ib < i1) ? __expf((float)db * (1.f / 3072.f)) : 0.f;
      se += ea + eb;
      VACC(ea, va.x, 0) VACC(ea, va.y, 4) VACC(ea, va.z, 8) VACC(ea, va.w, 12)
      VACC(eb, vw.x, 0) VACC(eb, vw.y, 4) VACC(eb, vw.z, 8) VACC(eb, vw.w, 12)
    }
#undef VACC
#pragma unroll
    for (int j = 0; j < 16; ++j) {
      acc[j] += __shfl_xor(acc[j], 16);
      acc[j] += __shfl_xor(acc[j], 32);
    }
    se += __shfl_xor(se, 16);
    se += __shfl_xor(se, 32);
    if (g == 0) {
      float inv = (se > 0.f) ? 1.0f / se : 0.f;
      float bias = (se > 0.f) ? -8.0f : 0.f;   // deg-0 node: attn out = 0
      long ob = (long)n * 256 + sub * 16;
      u16x8 sv0 = *(const u16x8*)&s1b[ob];
      u16x8 sv1 = *(const u16x8*)&s1b[ob + 8];
      u16x8 h0, h1;
#pragma unroll
      for (int j = 0; j < 8; ++j) {
        float v0 = fmaf(acc[j] * inv, 0.0625f, bias);
        float v1 = fmaf(acc[8 + j] * inv, 0.0625f, bias);
        h0[j] = (short)f2bf(fmaxf(v0 + bf2f((unsigned short)sv0[j]), 0.f));
        h1[j] = (short)f2bf(fmaxf(v1 + bf2f((unsigned short)sv1[j]), 0.f));
      }
      *(u16x8*)&s1b[ob] = h0;
      *(u16x8*)&s1b[ob + 8] = h1;
    }
  }
}

// ---------------- layer-2 linear via MFMA: [NPAD x 256] @ [256 x 32] ----------------
__global__ __launch_bounds__(256) void lin2_kernel(const unsigned short* __restrict__ hb,
                                                   const unsigned short* __restrict__ w2bt,
                                                   const float* __restrict__ bias2,
                                                   float* __restrict__ qs2, float* __restrict__ kv2) {
  __shared__ unsigned short Bs2[32 * 264];
  __shared__ float bsh[32];
  for (int i = threadIdx.x; i < 32 * 32; i += 256) {
    int r = i >> 5, cc = i & 31;
    *(u16x8*)&Bs2[r * 264 + cc * 8] = *(const u16x8*)&w2bt[r * 256 + cc * 8];
  }
  if (threadIdx.x < 32) bsh[threadIdx.x] = (threadIdx.x < 20) ? bias2[threadIdx.x] : 0.f;
  __syncthreads();
  int w = threadIdx.x >> 6, l = threadIdx.x & 63;
  long row0 = (long)blockIdx.x * 128 + w * 32;
  int lr = l & 15, c0 = l >> 4;
  f32x4 acc[2][2] = {};
  for (int kk = 0; kk < 8; ++kk) {
    int koff = kk * 32 + c0 * 8;
    bf16x8 af[2], bfv[2];
    af[0] = *(const bf16x8*)&hb[(row0 + lr) * 256 + koff];
    af[1] = *(const bf16x8*)&hb[(row0 + 16 + lr) * 256 + koff];
    bfv[0] = *(const bf16x8*)&Bs2[lr * 264 + koff];
    bfv[1] = *(const bf16x8*)&Bs2[(16 + lr) * 264 + koff];
#pragma unroll
    for (int mf = 0; mf < 2; ++mf)
#pragma unroll
      for (int nf = 0; nf < 2; ++nf)
        acc[mf][nf] = __builtin_amdgcn_mfma_f32_16x16x32_bf16(af[mf], bfv[nf], acc[mf][nf], 0, 0, 0);
  }
#pragma unroll
  for (int mf = 0; mf < 2; ++mf) {
#pragma unroll
    for (int nf = 0; nf < 2; ++nf) {
      int col = nf * 16 + lr;
#pragma unroll
      for (int i = 0; i < 4; ++i) {
        long n = row0 + mf * 16 + c0 * 4 + i;
        float v = acc[mf][nf][i] + bsh[col];
        if (col < 5) qs2[n * 12 + col] = v;
        else if (col < 15) kv2[n * 12 + (col - 5)] = v;
        else if (col < 20) qs2[n * 12 + (col - 10)] = v;
      }
    }
  }
}

// ---------------- layer-2 fused attention (1 thread per node) ----------------
__global__ void agg2_kernel(const float* __restrict__ qs2, const float* __restrict__ kv2,
                            const int* __restrict__ offsets, const int* __restrict__ csr_src,
                            float* __restrict__ out) {
  int n = blockIdx.x * 256 + threadIdx.x;
  if (n >= N_NODES) return;
  const float* bn = &qs2[(long)n * 12];
  const float is5 = 0.4472135954999579f;  // 1/sqrt(5)
  float q[5], acc[5] = {0, 0, 0, 0, 0}, se = 0.f;
#pragma unroll
  for (int c = 0; c < 5; ++c) q[c] = bn[c] * is5;
  int i0 = offsets[n], i1 = offsets[n + 1];
  for (int i = i0; i < i1; ++i) {
    int s = csr_src[i];
    const float4* ps = (const float4*)&kv2[(long)s * 12];
    float4 A = ps[0], B = ps[1], C = ps[2];
    float lg = q[0] * A.x + q[1] * A.y + q[2] * A.z + q[3] * A.w + q[4] * B.x;
    float ee = __expf(lg);
    se += ee;
    acc[0] += ee * B.y; acc[1] += ee * B.z; acc[2] += ee * B.w;
    acc[3] += ee * C.x; acc[4] += ee * C.y;
  }
  float inv = 1.f / (se + 1e-16f);
#pragma unroll
  for (int c = 0; c < 5; ++c) out[(long)n * 5 + c] = acc[c] * inv + bn[5 + c];
}

// ---------------- launch ----------------
extern "C" void kernel_launch(void* const* d_in, const int* in_sizes, int n_in,
                              void* d_out, int out_size, void* d_ws, size_t ws_size,
                              hipStream_t stream) {
  (void)in_sizes; (void)n_in; (void)out_size; (void)ws_size;
  const float* x   = (const float*)d_in[0];
  const int* eidx  = (const int*)d_in[1];
  const int* esrc  = eidx;
  const int* edst  = eidx + N_EDGES;
  const float* Wq1 = (const float*)d_in[2];  const float* bq1 = (const float*)d_in[3];
  const float* Wk1 = (const float*)d_in[4];  const float* bk1 = (const float*)d_in[5];
  const float* Wv1 = (const float*)d_in[6];  const float* bv1 = (const float*)d_in[7];
  const float* Ws1 = (const float*)d_in[8];  const float* bs1 = (const float*)d_in[9];
  const float* Wq2 = (const float*)d_in[10]; const float* bq2 = (const float*)d_in[11];
  const float* Wk2 = (const float*)d_in[12]; const float* bk2 = (const float*)d_in[13];
  const float* Wv2 = (const float*)d_in[14]; const float* bv2 = (const float*)d_in[15];
  const float* Ws2 = (const float*)d_in[16]; const float* bs2 = (const float*)d_in[17];

  char* p = (char*)d_ws;
  auto take = [&](size_t bytes) { char* r = p; p += (bytes + 255) & ~(size_t)255; return r; };
  unsigned short* xb  = (unsigned short*)take((size_t)NPAD * 384 * 2);
  unsigned short* wbt = (unsigned short*)take((size_t)1024 * 384 * 2);
  float* bias1        = (float*)take(1024 * 4);
  char* qb8           = (char*)take((size_t)NPAD * 256);
  unsigned char* kvb  = (unsigned char*)take((size_t)NPAD * 512);
  unsigned short* s1b = (unsigned short*)take((size_t)NPAD * 256 * 2);
  unsigned short* w2bt = (unsigned short*)take(32 * 256 * 2);
  float* bias2        = (float*)take(32 * 4);
  float* qs2          = (float*)take((size_t)NPAD * 12 * 4);
  float* kv2          = (float*)take((size_t)NPAD * 12 * 4);
  int* counts         = (int*)take((size_t)N_NODES * 4);
  int* offsets        = (int*)take((size_t)(N_NODES + 1) * 4);
  int* cursor         = (int*)take((size_t)N_NODES * 4);
  int* csr_src        = (int*)take((size_t)N_EDGES * 4);
  int* scan_tmp       = (int*)take((size_t)N_NODES * 4);
  int* scan_bsum      = (int*)take(256 * 4);
  int* scan_bbase     = (int*)take(256 * 4);

  hipMemsetAsync(counts, 0, (size_t)N_NODES * 4, stream);
  hist_kernel<<<(N_EDGES + 255) / 256, 256, 0, stream>>>(edst, counts, N_EDGES);
  scan1_kernel<<<SCAN_B, 256, 0, stream>>>(counts, scan_tmp, scan_bsum, N_NODES);
  scan2_kernel<<<1, 256, 0, stream>>>(scan_bsum, scan_bbase, SCAN_B);
  scan3_kernel<<<SCAN_B, 256, 0, stream>>>(scan_tmp, scan_bbase, offsets, cursor, N_NODES, N_EDGES);
  scatter_kernel<<<(N_EDGES + 255) / 256, 256, 0, stream>>>(esrc, edst, cursor, csr_src, N_EDGES);
  convert_x_kernel<<<(NPAD * 384 / 8 + 255) / 256, 256, 0, stream>>>(x, xb, N_NODES * 384, NPAD * 384);
  pack_w1_kernel<<<(1024 * 384 + 255) / 256, 256, 0, stream>>>(Wq1, Wk1, Wv1, Ws1, bq1, bk1, bv1, bs1, wbt, bias1);
  pack_w2_kernel<<<(32 * 256 + 255) / 256, 256, 0, stream>>>(Wq2, Wk2, Wv2, Ws2, bq2, bk2, bv2, bs2, w2bt, bias2);
  gemm1_kernel<<<((NPAD / 128 + 7) / 8) * 32, 512, 0, stream>>>(xb, wbt, bias1, qb8, kvb, s1b);
  agg1_kernel<<<2048, 256, 0, stream>>>(qb8, kvb, s1b, offsets, csr_src);
  lin2_kernel<<<NPAD / 128, 256, 0, stream>>>(s1b, w2bt, bias2, qs2, kv2);
  agg2_kernel<<<(N_NODES + 255) / 256, 256, 0, stream>>>(qs2, kv2, offsets, csr_src, (float*)d_out);
}